// Round 5
// baseline (248.946 us; speedup 1.0000x reference)
//
#include <hip/hip_runtime.h>
#include <math.h>

#define T_TOK 2048
#define H_DIM 1024
#define M_DIM 512
#define E_NUM 32
#define TOPK  4

#define BT    64       // tokens per tile
#define BK    32       // k per step
#define GU_BM 64       // gateup N-tile
#define DN_BH 128      // down N-tile
#define MAX_TILES 160  // sum ceil(cnt_e/64) <= 31 + 8192/64 = 159

typedef __bf16 bf16x8 __attribute__((ext_vector_type(8)));
typedef float f32x4 __attribute__((ext_vector_type(4)));
typedef unsigned short u16x8 __attribute__((ext_vector_type(8)));
typedef unsigned short u16x4 __attribute__((ext_vector_type(4)));

__device__ __forceinline__ unsigned short f2bf(float f) {
  unsigned u = __float_as_uint(f);
  return (unsigned short)((u + 0x7fffu + ((u >> 16) & 1u)) >> 16);
}
__device__ __forceinline__ float bf2f(unsigned short h) {
  return __uint_as_float(((unsigned)h) << 16);
}
__device__ __forceinline__ f32x4 mfma16(bf16x8 a, bf16x8 b, f32x4 c) {
  return __builtin_amdgcn_mfma_f32_16x16x32_bf16(a, b, c, 0, 0, 0);
}

// ---------------- K1: gating + x split + scatter (fused) ---------------------
__global__ __launch_bounds__(256) void gating_kernel(
    const float* __restrict__ x, const float* __restrict__ gate_w,
    unsigned short* __restrict__ xh, unsigned short* __restrict__ xl,
    float* __restrict__ topk_w, int* __restrict__ cursors,
    int* __restrict__ tok_list) {
  __shared__ float xr[H_DIM];
  __shared__ float logits[E_NUM];
  int t = blockIdx.x;
  int tid = threadIdx.x;
  const float* xrow = x + (size_t)t * H_DIM;
  float4 v = *(const float4*)(xrow + tid * 4);
  *(float4*)(xr + tid * 4) = v;
  {  // split this thread's 4 elems to hi/lo bf16
    float f[4] = {v.x, v.y, v.z, v.w};
    u16x4 hv, lv;
    #pragma unroll
    for (int j = 0; j < 4; ++j) {
      unsigned short h = f2bf(f[j]);
      hv[j] = h;
      lv[j] = f2bf(f[j] - bf2f(h));
    }
    *(u16x4*)(xh + (size_t)t * H_DIM + tid * 4) = hv;
    *(u16x4*)(xl + (size_t)t * H_DIM + tid * 4) = lv;
  }
  __syncthreads();
  int wave = tid >> 6, lane = tid & 63;
  const float4* x4 = (const float4*)xr;
  for (int e8 = 0; e8 < 8; ++e8) {
    int e = wave * 8 + e8;
    const float4* g4 = (const float4*)(gate_w + (size_t)e * H_DIM);
    float p = 0.f;
    #pragma unroll
    for (int i = 0; i < 4; ++i) {
      float4 a = x4[lane + i * 64];
      float4 b = g4[lane + i * 64];
      p += a.x * b.x + a.y * b.y + a.z * b.z + a.w * b.w;
    }
    for (int off = 32; off > 0; off >>= 1) p += __shfl_down(p, off, 64);
    if (lane == 0) logits[e] = p;
  }
  __syncthreads();
  if (tid == 0) {
    float vv[E_NUM];
    for (int e = 0; e < E_NUM; ++e) vv[e] = logits[e];
    int ids[TOPK]; float vals[TOPK];
    for (int k = 0; k < TOPK; ++k) {
      int bi = 0; float bv = -1e30f;
      for (int e = 0; e < E_NUM; ++e) if (vv[e] > bv) { bv = vv[e]; bi = e; }
      ids[k] = bi; vals[k] = bv; vv[bi] = -1e30f;
    }
    float m = vals[0];
    float w[TOPK]; float s = 0.f;
    for (int k = 0; k < TOPK; ++k) { w[k] = expf(vals[k] - m); s += w[k]; }
    float inv = 1.f / s;
    for (int k = 0; k < TOPK; ++k) {
      int g = t * TOPK + k;
      topk_w[g] = w[k] * inv;
      int slot = atomicAdd(&cursors[ids[k]], 1);
      tok_list[ids[k] * T_TOK + slot] = g;
    }
  }
}

// ---------------- K2b: tile work list ----------------------------------------
__global__ void build_tiles(const int* __restrict__ cursors,
                            int* __restrict__ n_tiles, int* __restrict__ tile_list) {
  int lane = threadIdx.x;
  int nt = 0;
  if (lane < E_NUM) nt = (cursors[lane] + BT - 1) / BT;
  int pfx = nt;
  for (int off = 1; off < 64; off <<= 1) {
    int v = __shfl_up(pfx, off, 64);
    if (lane >= off) pfx += v;
  }
  int excl = pfx - nt;
  if (lane == E_NUM - 1) *n_tiles = pfx;
  if (lane < E_NUM)
    for (int i = 0; i < nt; ++i) tile_list[excl + i] = (lane << 8) | i;
}

// ---------------- K3: gateup — 64x64 tile, 256 thr, single-buf 2-barrier -----
// LDS layout (ushort idx): elem(row,k) at (row>>4)*512 + ((k>>3)&3)*128 + (row&15)*8 + (k&7)
// staging thread t -> row=(t>>6)*16+(t&15), kq=(t>>4)&3, LDS off = t*8 (lane-linear)
__global__ __launch_bounds__(256) void gateup_mfma(
    const unsigned short* __restrict__ xh, const unsigned short* __restrict__ xl,
    const float* __restrict__ w_gate, const float* __restrict__ w_up,
    const float* __restrict__ topk_w,
    const int* __restrict__ cursors, const int* __restrict__ tok_list,
    const int* __restrict__ n_tiles, const int* __restrict__ tile_list,
    unsigned short* __restrict__ mixed) {
  if (blockIdx.y >= *n_tiles) return;
  int tid = threadIdx.x;
  int entry = tile_list[blockIdx.y];
  int e = entry >> 8, tile = entry & 255;
  int cnt = cursors[e];
  int m0 = blockIdx.x * GU_BM;

  __shared__ unsigned short Ah[BT * BK], Al[BT * BK];      // 4 KB each
  __shared__ unsigned short Gs[GU_BM * BK], Us[GU_BM * BK];
  __shared__ int   ent[BT];
  __shared__ float rw[BT];

  if (tid < BT) {
    int idx = tile * BT + tid;
    int en = (idx < cnt) ? tok_list[e * T_TOK + idx] : -1;
    ent[tid] = en;
    rw[tid]  = (en >= 0) ? topk_w[en] : 0.f;
  }
  __syncthreads();

  int srow = ((tid >> 6) << 4) + (tid & 15);  // 0..63
  int skq  = (tid >> 4) & 3;
  int aen = ent[srow];
  if (aen < 0) aen = ent[0];  // garbage rows harmless: their out rows skipped
  const unsigned short* pAh = xh + (size_t)(aen >> 2) * H_DIM + skq * 8;
  const unsigned short* pAl = xl + (size_t)(aen >> 2) * H_DIM + skq * 8;
  const float* pG = w_gate + ((size_t)e * M_DIM + m0 + srow) * H_DIM + skq * 8;
  const float* pU = w_up   + ((size_t)e * M_DIM + m0 + srow) * H_DIM + skq * 8;
  int soff = tid * 8;

  int lane = tid & 63, wid = tid >> 6;
  int wr = (wid >> 1) * 32;  // 0,32
  int wc = (wid & 1) * 32;   // 0,32
  int l8 = lane * 8;

  f32x4 accg[2][2] = {}; f32x4 accu[2][2] = {};

  u16x8 rah0, ral0, rah1, ral1;
  float rg0[8], ru0[8], rg1[8], ru1[8];

#define GU_LOAD(S, k0_) { \
    rah##S = *(const u16x8*)(pAh + (k0_)); \
    ral##S = *(const u16x8*)(pAl + (k0_)); \
    *(float4*)(rg##S)     = *(const float4*)(pG + (k0_)); \
    *(float4*)(rg##S + 4) = *(const float4*)(pG + (k0_) + 4); \
    *(float4*)(ru##S)     = *(const float4*)(pU + (k0_)); \
    *(float4*)(ru##S + 4) = *(const float4*)(pU + (k0_) + 4); }

#define GU_STORE(S) { \
    u16x8 gq, uq; \
    _Pragma("unroll") \
    for (int j = 0; j < 8; ++j) { gq[j] = f2bf(rg##S[j]); uq[j] = f2bf(ru##S[j]); } \
    *(u16x8*)&Ah[soff] = rah##S; \
    *(u16x8*)&Al[soff] = ral##S; \
    *(u16x8*)&Gs[soff] = gq; \
    *(u16x8*)&Us[soff] = uq; }

#define GU_COMPUTE() { \
    int ab = (wr >> 4) * 512 + l8; \
    bf16x8 a0h = *(const bf16x8*)&Ah[ab]; \
    bf16x8 a1h = *(const bf16x8*)&Ah[ab + 512]; \
    bf16x8 a0l = *(const bf16x8*)&Al[ab]; \
    bf16x8 a1l = *(const bf16x8*)&Al[ab + 512]; \
    int nb = (wc >> 4) * 512 + l8; \
    bf16x8 g0 = *(const bf16x8*)&Gs[nb]; \
    bf16x8 g1 = *(const bf16x8*)&Gs[nb + 512]; \
    bf16x8 u0 = *(const bf16x8*)&Us[nb]; \
    bf16x8 u1 = *(const bf16x8*)&Us[nb + 512]; \
    accg[0][0] = mfma16(a0h, g0, accg[0][0]); \
    accg[0][0] = mfma16(a0l, g0, accg[0][0]); \
    accg[1][0] = mfma16(a1h, g0, accg[1][0]); \
    accg[1][0] = mfma16(a1l, g0, accg[1][0]); \
    accg[0][1] = mfma16(a0h, g1, accg[0][1]); \
    accg[0][1] = mfma16(a0l, g1, accg[0][1]); \
    accg[1][1] = mfma16(a1h, g1, accg[1][1]); \
    accg[1][1] = mfma16(a1l, g1, accg[1][1]); \
    accu[0][0] = mfma16(a0h, u0, accu[0][0]); \
    accu[0][0] = mfma16(a0l, u0, accu[0][0]); \
    accu[1][0] = mfma16(a1h, u0, accu[1][0]); \
    accu[1][0] = mfma16(a1l, u0, accu[1][0]); \
    accu[0][1] = mfma16(a0h, u1, accu[0][1]); \
    accu[0][1] = mfma16(a0l, u1, accu[0][1]); \
    accu[1][1] = mfma16(a1h, u1, accu[1][1]); \
    accu[1][1] = mfma16(a1l, u1, accu[1][1]); }

  GU_LOAD(0, 0);
  const int NK = H_DIM / BK;  // 32, even
  for (int ks = 0; ks < NK; ks += 2) {
    __syncthreads();                       // all waves done reading LDS
    GU_LOAD(1, (ks + 1) * BK);             // issue next loads early (1-iter window)
    GU_STORE(0);
    __syncthreads();                       // staging visible
    GU_COMPUTE();
    __syncthreads();
    if (ks + 2 < NK) GU_LOAD(0, (ks + 2) * BK);
    GU_STORE(1);
    __syncthreads();
    GU_COMPUTE();
  }

  #pragma unroll
  for (int mf = 0; mf < 2; ++mf) {
    #pragma unroll
    for (int j = 0; j < 4; ++j) {
      int tr = wr + mf * 16 + (lane >> 4) * 4 + j;
      int en = ent[tr];
      if (en < 0) continue;
      float w = rw[tr];
      #pragma unroll
      for (int nf = 0; nf < 2; ++nf) {
        float g = accg[mf][nf][j], u = accu[mf][nf][j];
        float val = (g / (1.f + __expf(-g))) * u * w;
        mixed[(size_t)en * M_DIM + m0 + wc + nf * 16 + (lane & 15)] = f2bf(val);
      }
    }
  }
}

// ---------------- K4: down — 64x128 tile, 256 thr, single-buf 2-barrier ------
__global__ __launch_bounds__(256) void down_mfma(
    const float* __restrict__ w_down, const unsigned short* __restrict__ mixed,
    const int* __restrict__ cursors, const int* __restrict__ tok_list,
    const int* __restrict__ n_tiles, const int* __restrict__ tile_list,
    float* __restrict__ out) {
  if (blockIdx.y >= *n_tiles) return;
  int tid = threadIdx.x;
  int entry = tile_list[blockIdx.y];
  int e = entry >> 8, tile = entry & 255;
  int cnt = cursors[e];
  int h0 = blockIdx.x * DN_BH;

  __shared__ unsigned short As[BT * BK];      // 4 KB
  __shared__ unsigned short Bs[DN_BH * BK];   // 8 KB
  __shared__ int ent[BT];

  if (tid < BT) {
    int idx = tile * BT + tid;
    ent[tid] = (idx < cnt) ? tok_list[e * T_TOK + idx] : -1;
  }
  __syncthreads();

  int srow = ((tid >> 6) << 4) + (tid & 15);  // 0..63
  int skq  = (tid >> 4) & 3;
  int aen = ent[srow];
  if (aen < 0) aen = ent[0];
  const unsigned short* pA = mixed + (size_t)aen * M_DIM + skq * 8;
  const float* pB0 = w_down + ((size_t)e * H_DIM + h0 + srow) * M_DIM + skq * 8;
  const float* pB1 = pB0 + (size_t)64 * M_DIM;
  int soff = tid * 8;

  int lane = tid & 63, wid = tid >> 6;
  int wr = (wid >> 1) * 32;  // 0,32
  int wc = (wid & 1) * 64;   // 0,64
  int l8 = lane * 8;

  f32x4 acc[2][4] = {};
  u16x8 ra0, ra1;
  float rb00[8], rb01[8], rb10[8], rb11[8];

#define DN_LOAD(S, k0_) { \
    ra##S = *(const u16x8*)(pA + (k0_)); \
    *(float4*)(rb##S##0)     = *(const float4*)(pB0 + (k0_)); \
    *(float4*)(rb##S##0 + 4) = *(const float4*)(pB0 + (k0_) + 4); \
    *(float4*)(rb##S##1)     = *(const float4*)(pB1 + (k0_)); \
    *(float4*)(rb##S##1 + 4) = *(const float4*)(pB1 + (k0_) + 4); }

#define DN_STORE(S) { \
    u16x8 b0q, b1q; \
    _Pragma("unroll") \
    for (int j = 0; j < 8; ++j) { b0q[j] = f2bf(rb##S##0[j]); b1q[j] = f2bf(rb##S##1[j]); } \
    *(u16x8*)&As[soff] = ra##S; \
    *(u16x8*)&Bs[soff] = b0q; \
    *(u16x8*)&Bs[2048 + soff] = b1q; }

#define DN_COMPUTE() { \
    int ab = (wr >> 4) * 512 + l8; \
    bf16x8 a0 = *(const bf16x8*)&As[ab]; \
    bf16x8 a1 = *(const bf16x8*)&As[ab + 512]; \
    int nb = (wc >> 4) * 512 + l8; \
    bf16x8 b0 = *(const bf16x8*)&Bs[nb]; \
    bf16x8 b1 = *(const bf16x8*)&Bs[nb + 512]; \
    bf16x8 b2 = *(const bf16x8*)&Bs[nb + 1024]; \
    bf16x8 b3 = *(const bf16x8*)&Bs[nb + 1536]; \
    acc[0][0] = mfma16(a0, b0, acc[0][0]); \
    acc[1][0] = mfma16(a1, b0, acc[1][0]); \
    acc[0][1] = mfma16(a0, b1, acc[0][1]); \
    acc[1][1] = mfma16(a1, b1, acc[1][1]); \
    acc[0][2] = mfma16(a0, b2, acc[0][2]); \
    acc[1][2] = mfma16(a1, b2, acc[1][2]); \
    acc[0][3] = mfma16(a0, b3, acc[0][3]); \
    acc[1][3] = mfma16(a1, b3, acc[1][3]); }

  DN_LOAD(0, 0);
  const int NK = M_DIM / BK;  // 16, even
  for (int ks = 0; ks < NK; ks += 2) {
    __syncthreads();
    DN_LOAD(1, (ks + 1) * BK);
    DN_STORE(0);
    __syncthreads();
    DN_COMPUTE();
    __syncthreads();
    if (ks + 2 < NK) DN_LOAD(0, (ks + 2) * BK);
    DN_STORE(1);
    __syncthreads();
    DN_COMPUTE();
  }

  #pragma unroll
  for (int mf = 0; mf < 2; ++mf) {
    #pragma unroll
    for (int j = 0; j < 4; ++j) {
      int tr = wr + mf * 16 + (lane >> 4) * 4 + j;
      int en = ent[tr];
      if (en < 0) continue;
      int t = en >> 2;
      #pragma unroll
      for (int nf = 0; nf < 4; ++nf)
        atomicAdd(&out[(size_t)t * H_DIM + h0 + wc + nf * 16 + (lane & 15)],
                  acc[mf][nf][j]);
    }
  }
}

extern "C" void kernel_launch(void* const* d_in, const int* in_sizes, int n_in,
                              void* d_out, int out_size, void* d_ws, size_t ws_size,
                              hipStream_t stream) {
  const float* x      = (const float*)d_in[0];
  const float* gate_w = (const float*)d_in[1];
  const float* w_gate = (const float*)d_in[2];
  const float* w_up   = (const float*)d_in[3];
  const float* w_down = (const float*)d_in[4];
  float* out = (float*)d_out;

  char* ws = (char*)d_ws;
  size_t off = 0;
  float* topk_w    = (float*)(ws + off); off += (size_t)T_TOK * TOPK * 4;
  int*   cursors   = (int*)(ws + off);   off += 256;
  int*   n_tiles   = (int*)(ws + off);   off += 64;
  int*   tile_list = (int*)(ws + off);   off += MAX_TILES * 4 + 64;
  int*   tok_list  = (int*)(ws + off);   off += (size_t)E_NUM * T_TOK * 4;
  unsigned short* x_hi  = (unsigned short*)(ws + off); off += (size_t)T_TOK * H_DIM * 2;
  unsigned short* x_lo  = (unsigned short*)(ws + off); off += (size_t)T_TOK * H_DIM * 2;
  unsigned short* mixed = (unsigned short*)(ws + off); off += (size_t)T_TOK * TOPK * M_DIM * 2;

  hipMemsetAsync(cursors, 0, E_NUM * sizeof(int), stream);
  hipMemsetAsync(out, 0, (size_t)T_TOK * H_DIM * sizeof(float), stream);

  gating_kernel<<<T_TOK, 256, 0, stream>>>(x, gate_w, x_hi, x_lo, topk_w,
                                           cursors, tok_list);
  build_tiles<<<1, 64, 0, stream>>>(cursors, n_tiles, tile_list);
  gateup_mfma<<<dim3(M_DIM / GU_BM, MAX_TILES), 256, 0, stream>>>(
      x_hi, x_lo, w_gate, w_up, topk_w, cursors, tok_list, n_tiles, tile_list, mixed);
  down_mfma<<<dim3(H_DIM / DN_BH, MAX_TILES), 256, 0, stream>>>(
      w_down, mixed, cursors, tok_list, n_tiles, tile_list, out);
}

// Round 6
// 212.783 us; speedup vs baseline: 1.1700x; 1.1700x over previous
//
#include <hip/hip_runtime.h>
#include <math.h>

#define T_TOK 2048
#define H_DIM 1024
#define M_DIM 512
#define E_NUM 32
#define TOPK  4

#define BT    64       // tokens per tile
#define BK    32       // k per step
#define GU_BM 64       // gateup N-tile
#define DN_BH 128      // down N-tile
#define MAX_TILES 160  // sum ceil(cnt_e/64) <= 31 + 8192/64 = 159

typedef __bf16 bf16x8 __attribute__((ext_vector_type(8)));
typedef float f32x4 __attribute__((ext_vector_type(4)));
typedef unsigned short u16x4 __attribute__((ext_vector_type(4)));

__device__ __forceinline__ unsigned short f2bf(float f) {
  unsigned u = __float_as_uint(f);
  return (unsigned short)((u + 0x7fffu + ((u >> 16) & 1u)) >> 16);
}
__device__ __forceinline__ float bf2f(unsigned short h) {
  return __uint_as_float(((unsigned)h) << 16);
}
__device__ __forceinline__ f32x4 mfma16(bf16x8 a, bf16x8 b, f32x4 c) {
  return __builtin_amdgcn_mfma_f32_16x16x32_bf16(a, b, c, 0, 0, 0);
}
__device__ __forceinline__ void gload16(const void* g, void* l) {
  __builtin_amdgcn_global_load_lds(
      (const __attribute__((address_space(1))) unsigned int*)g,
      (__attribute__((address_space(3))) unsigned int*)l, 16, 0, 0);
}
__device__ __forceinline__ bf16x8 cvt8(f32x4 a, f32x4 b) {
  bf16x8 r;
  #pragma unroll
  for (int j = 0; j < 4; ++j) { r[j] = (__bf16)a[j]; r[4 + j] = (__bf16)b[j]; }
  return r;
}

// ---------------- K1: gating + x split + scatter (fused) ---------------------
__global__ __launch_bounds__(256) void gating_kernel(
    const float* __restrict__ x, const float* __restrict__ gate_w,
    unsigned short* __restrict__ xh, unsigned short* __restrict__ xl,
    float* __restrict__ topk_w, int* __restrict__ cursors,
    int* __restrict__ tok_list) {
  __shared__ float xr[H_DIM];
  __shared__ float logits[E_NUM];
  int t = blockIdx.x;
  int tid = threadIdx.x;
  const float* xrow = x + (size_t)t * H_DIM;
  float4 v = *(const float4*)(xrow + tid * 4);
  *(float4*)(xr + tid * 4) = v;
  {  // split this thread's 4 elems to hi/lo bf16
    float f[4] = {v.x, v.y, v.z, v.w};
    u16x4 hv, lv;
    #pragma unroll
    for (int j = 0; j < 4; ++j) {
      unsigned short h = f2bf(f[j]);
      hv[j] = h;
      lv[j] = f2bf(f[j] - bf2f(h));
    }
    *(u16x4*)(xh + (size_t)t * H_DIM + tid * 4) = hv;
    *(u16x4*)(xl + (size_t)t * H_DIM + tid * 4) = lv;
  }
  __syncthreads();
  int wave = tid >> 6, lane = tid & 63;
  const float4* x4 = (const float4*)xr;
  for (int e8 = 0; e8 < 8; ++e8) {
    int e = wave * 8 + e8;
    const float4* g4 = (const float4*)(gate_w + (size_t)e * H_DIM);
    float p = 0.f;
    #pragma unroll
    for (int i = 0; i < 4; ++i) {
      float4 a = x4[lane + i * 64];
      float4 b = g4[lane + i * 64];
      p += a.x * b.x + a.y * b.y + a.z * b.z + a.w * b.w;
    }
    for (int off = 32; off > 0; off >>= 1) p += __shfl_down(p, off, 64);
    if (lane == 0) logits[e] = p;
  }
  __syncthreads();
  if (tid == 0) {
    float vv[E_NUM];
    for (int e = 0; e < E_NUM; ++e) vv[e] = logits[e];
    int ids[TOPK]; float vals[TOPK];
    for (int k = 0; k < TOPK; ++k) {
      int bi = 0; float bv = -1e30f;
      for (int e = 0; e < E_NUM; ++e) if (vv[e] > bv) { bv = vv[e]; bi = e; }
      ids[k] = bi; vals[k] = bv; vv[bi] = -1e30f;
    }
    float m = vals[0];
    float w[TOPK]; float s = 0.f;
    for (int k = 0; k < TOPK; ++k) { w[k] = expf(vals[k] - m); s += w[k]; }
    float inv = 1.f / s;
    for (int k = 0; k < TOPK; ++k) {
      int g = t * TOPK + k;
      topk_w[g] = w[k] * inv;
      int slot = atomicAdd(&cursors[ids[k]], 1);
      tok_list[ids[k] * T_TOK + slot] = g;
    }
  }
}

// ---------------- K2b: tile work list ----------------------------------------
__global__ void build_tiles(const int* __restrict__ cursors,
                            int* __restrict__ n_tiles, int* __restrict__ tile_list) {
  int lane = threadIdx.x;
  int nt = 0;
  if (lane < E_NUM) nt = (cursors[lane] + BT - 1) / BT;
  int pfx = nt;
  for (int off = 1; off < 64; off <<= 1) {
    int v = __shfl_up(pfx, off, 64);
    if (lane >= off) pfx += v;
  }
  int excl = pfx - nt;
  if (lane == E_NUM - 1) *n_tiles = pfx;
  if (lane < E_NUM)
    for (int i = 0; i < nt; ++i) tile_list[excl + i] = (lane << 8) | i;
}

// ---------------- K3: gateup — global_load_lds staging, single buffer --------
// A LDS (bf16, per matrix): elem(row,k) at ushort idx (row>>4)*512 + (k>>3)*128
//   + (row&15)*8 + (k&7). DMA chunk c=tid (16B): lane-linear dest c*16B.
// B LDS (f32): elem(row,k) at f32 idx (row>>4)*512 + (k>>3)*128 + (row&15)*8
//   + (k&7). DMA chunk c (16B=4 f32): row=(c>>7)*16+((c>>1)&15),
//   k0=((c>>5)&3)*8+(c&1)*4; dest c*16B (lane-linear).
// Fragment read (both): group g, lane l -> idx g*512 + l*8 (conflict-free).
__global__ __launch_bounds__(256, 6) void gateup_mfma(
    const unsigned short* __restrict__ xh, const unsigned short* __restrict__ xl,
    const float* __restrict__ w_gate, const float* __restrict__ w_up,
    const float* __restrict__ topk_w,
    const int* __restrict__ cursors, const int* __restrict__ tok_list,
    const int* __restrict__ n_tiles, const int* __restrict__ tile_list,
    unsigned short* __restrict__ mixed) {
  if (blockIdx.y >= *n_tiles) return;
  int tid = threadIdx.x;
  int entry = tile_list[blockIdx.y];
  int e = entry >> 8, tile = entry & 255;
  int cnt = cursors[e];
  int m0 = blockIdx.x * GU_BM;

  __shared__ unsigned short Ah[BT * BK];   // 4 KB
  __shared__ unsigned short Al[BT * BK];   // 4 KB
  __shared__ float Gs[GU_BM * BK];         // 8 KB
  __shared__ float Us[GU_BM * BK];         // 8 KB
  __shared__ int   ent[BT];
  __shared__ float rw[BT];

  if (tid < BT) {
    int idx = tile * BT + tid;
    int en = (idx < cnt) ? tok_list[e * T_TOK + idx] : -1;
    ent[tid] = en;
    rw[tid]  = (en >= 0) ? topk_w[en] : 0.f;
  }
  __syncthreads();

  // A staging: chunk c = tid; row=(c>>6)*16+(c&15), k-octet=(c>>4)&3
  int arow = ((tid >> 6) << 4) + (tid & 15);
  int askq = (tid >> 4) & 3;
  int aen = ent[arow]; if (aen < 0) aen = ent[0];
  const unsigned short* gAh = xh + (size_t)(aen >> 2) * H_DIM + askq * 8;
  const unsigned short* gAl = xl + (size_t)(aen >> 2) * H_DIM + askq * 8;
  unsigned short* lAh = &Ah[tid * 8];
  unsigned short* lAl = &Al[tid * 8];

  // B staging: 2 chunks each for G and U
  int c0 = tid, c1 = tid + 256;
  int br0 = ((c0 >> 7) << 4) + ((c0 >> 1) & 15), bk0 = ((c0 >> 5) & 3) * 8 + (c0 & 1) * 4;
  int br1 = ((c1 >> 7) << 4) + ((c1 >> 1) & 15), bk1 = ((c1 >> 5) & 3) * 8 + (c1 & 1) * 4;
  const float* gG0 = w_gate + ((size_t)e * M_DIM + m0 + br0) * H_DIM + bk0;
  const float* gG1 = w_gate + ((size_t)e * M_DIM + m0 + br1) * H_DIM + bk1;
  const float* gU0 = w_up   + ((size_t)e * M_DIM + m0 + br0) * H_DIM + bk0;
  const float* gU1 = w_up   + ((size_t)e * M_DIM + m0 + br1) * H_DIM + bk1;
  float* lG0 = &Gs[c0 * 4]; float* lG1 = &Gs[c1 * 4];
  float* lU0 = &Us[c0 * 4]; float* lU1 = &Us[c1 * 4];

  int lane = tid & 63, wid = tid >> 6;
  int wr = (wid >> 1) * 32;  // 0,32
  int wc = (wid & 1) * 32;   // 0,32
  int l8 = lane * 8;

  f32x4 accg[2][2] = {}; f32x4 accu[2][2] = {};

  const int NK = H_DIM / BK;  // 32
  for (int ks = 0; ks < NK; ++ks) {
    int ka = ks * BK;
    gload16(gAh + ka, lAh);
    gload16(gAl + ka, lAl);
    gload16(gG0 + ka, lG0);
    gload16(gG1 + ka, lG1);
    gload16(gU0 + ka, lU0);
    gload16(gU1 + ka, lU1);
    __syncthreads();  // drains vmcnt(0): all DMA landed

    int ab = (wr >> 4) * 512 + l8;
    bf16x8 a0h = *(const bf16x8*)&Ah[ab];
    bf16x8 a1h = *(const bf16x8*)&Ah[ab + 512];
    bf16x8 a0l = *(const bf16x8*)&Al[ab];
    bf16x8 a1l = *(const bf16x8*)&Al[ab + 512];
    #pragma unroll
    for (int nf = 0; nf < 2; ++nf) {
      int nb = ((wc >> 4) + nf) * 512 + l8;
      bf16x8 g = cvt8(*(const f32x4*)&Gs[nb], *(const f32x4*)&Gs[nb + 4]);
      bf16x8 u = cvt8(*(const f32x4*)&Us[nb], *(const f32x4*)&Us[nb + 4]);
      accg[0][nf] = mfma16(a0h, g, accg[0][nf]);
      accg[0][nf] = mfma16(a0l, g, accg[0][nf]);
      accg[1][nf] = mfma16(a1h, g, accg[1][nf]);
      accg[1][nf] = mfma16(a1l, g, accg[1][nf]);
      accu[0][nf] = mfma16(a0h, u, accu[0][nf]);
      accu[0][nf] = mfma16(a0l, u, accu[0][nf]);
      accu[1][nf] = mfma16(a1h, u, accu[1][nf]);
      accu[1][nf] = mfma16(a1l, u, accu[1][nf]);
    }
    __syncthreads();  // all reads done before next DMA overwrites
  }

  #pragma unroll
  for (int mf = 0; mf < 2; ++mf) {
    #pragma unroll
    for (int j = 0; j < 4; ++j) {
      int tr = wr + mf * 16 + (lane >> 4) * 4 + j;
      int en = ent[tr];
      if (en < 0) continue;
      float w = rw[tr];
      #pragma unroll
      for (int nf = 0; nf < 2; ++nf) {
        float g = accg[mf][nf][j], u = accu[mf][nf][j];
        float val = (g / (1.f + __expf(-g))) * u * w;
        __bf16 bv = (__bf16)val;
        mixed[(size_t)en * M_DIM + m0 + wc + nf * 16 + (lane & 15)] =
            *(unsigned short*)&bv;
      }
    }
  }
}

// ---------------- K4: down — global_load_lds staging, single buffer ----------
__global__ __launch_bounds__(256, 7) void down_mfma(
    const float* __restrict__ w_down, const unsigned short* __restrict__ mixed,
    const int* __restrict__ cursors, const int* __restrict__ tok_list,
    const int* __restrict__ n_tiles, const int* __restrict__ tile_list,
    float* __restrict__ out) {
  if (blockIdx.y >= *n_tiles) return;
  int tid = threadIdx.x;
  int entry = tile_list[blockIdx.y];
  int e = entry >> 8, tile = entry & 255;
  int cnt = cursors[e];
  int h0 = blockIdx.x * DN_BH;

  __shared__ unsigned short As[BT * BK];   // 4 KB
  __shared__ float Bs[DN_BH * BK];         // 16 KB
  __shared__ int ent[BT];

  if (tid < BT) {
    int idx = tile * BT + tid;
    ent[tid] = (idx < cnt) ? tok_list[e * T_TOK + idx] : -1;
  }
  __syncthreads();

  // A: chunk c = tid
  int arow = ((tid >> 6) << 4) + (tid & 15);
  int askq = (tid >> 4) & 3;
  int aen = ent[arow]; if (aen < 0) aen = ent[0];
  const unsigned short* gA = mixed + (size_t)aen * M_DIM + askq * 8;
  unsigned short* lA = &As[tid * 8];

  // B: 4 chunks c = tid + 256*i
  const float* gB[4];
  float* lB[4];
  #pragma unroll
  for (int i = 0; i < 4; ++i) {
    int c = tid + 256 * i;
    int row = ((c >> 7) << 4) + ((c >> 1) & 15);
    int kof = ((c >> 5) & 3) * 8 + (c & 1) * 4;
    gB[i] = w_down + ((size_t)e * H_DIM + h0 + row) * M_DIM + kof;
    lB[i] = &Bs[c * 4];
  }

  int lane = tid & 63, wid = tid >> 6;
  int wr = (wid >> 1) * 32;  // 0,32
  int wc = (wid & 1) * 64;   // 0,64
  int l8 = lane * 8;

  f32x4 acc[2][4] = {};

  const int NK = M_DIM / BK;  // 16
  for (int ks = 0; ks < NK; ++ks) {
    int ka = ks * BK;
    gload16(gA + ka, lA);
    gload16(gB[0] + ka, lB[0]);
    gload16(gB[1] + ka, lB[1]);
    gload16(gB[2] + ka, lB[2]);
    gload16(gB[3] + ka, lB[3]);
    __syncthreads();

    int ab = (wr >> 4) * 512 + l8;
    bf16x8 a0 = *(const bf16x8*)&As[ab];
    bf16x8 a1 = *(const bf16x8*)&As[ab + 512];
    #pragma unroll
    for (int nf = 0; nf < 4; ++nf) {
      int nb = ((wc >> 4) + nf) * 512 + l8;
      bf16x8 b = cvt8(*(const f32x4*)&Bs[nb], *(const f32x4*)&Bs[nb + 4]);
      acc[0][nf] = mfma16(a0, b, acc[0][nf]);
      acc[1][nf] = mfma16(a1, b, acc[1][nf]);
    }
    __syncthreads();
  }

  #pragma unroll
  for (int mf = 0; mf < 2; ++mf) {
    #pragma unroll
    for (int j = 0; j < 4; ++j) {
      int tr = wr + mf * 16 + (lane >> 4) * 4 + j;
      int en = ent[tr];
      if (en < 0) continue;
      int t = en >> 2;
      #pragma unroll
      for (int nf = 0; nf < 4; ++nf)
        atomicAdd(&out[(size_t)t * H_DIM + h0 + wc + nf * 16 + (lane & 15)],
                  acc[mf][nf][j]);
    }
  }
}

extern "C" void kernel_launch(void* const* d_in, const int* in_sizes, int n_in,
                              void* d_out, int out_size, void* d_ws, size_t ws_size,
                              hipStream_t stream) {
  const float* x      = (const float*)d_in[0];
  const float* gate_w = (const float*)d_in[1];
  const float* w_gate = (const float*)d_in[2];
  const float* w_up   = (const float*)d_in[3];
  const float* w_down = (const float*)d_in[4];
  float* out = (float*)d_out;

  char* ws = (char*)d_ws;
  size_t off = 0;
  float* topk_w    = (float*)(ws + off); off += (size_t)T_TOK * TOPK * 4;
  int*   cursors   = (int*)(ws + off);   off += 256;
  int*   n_tiles   = (int*)(ws + off);   off += 64;
  int*   tile_list = (int*)(ws + off);   off += MAX_TILES * 4 + 64;
  int*   tok_list  = (int*)(ws + off);   off += (size_t)E_NUM * T_TOK * 4;
  unsigned short* x_hi  = (unsigned short*)(ws + off); off += (size_t)T_TOK * H_DIM * 2;
  unsigned short* x_lo  = (unsigned short*)(ws + off); off += (size_t)T_TOK * H_DIM * 2;
  unsigned short* mixed = (unsigned short*)(ws + off); off += (size_t)T_TOK * TOPK * M_DIM * 2;

  hipMemsetAsync(cursors, 0, E_NUM * sizeof(int), stream);
  hipMemsetAsync(out, 0, (size_t)T_TOK * H_DIM * sizeof(float), stream);

  gating_kernel<<<T_TOK, 256, 0, stream>>>(x, gate_w, x_hi, x_lo, topk_w,
                                           cursors, tok_list);
  build_tiles<<<1, 64, 0, stream>>>(cursors, n_tiles, tile_list);
  gateup_mfma<<<dim3(M_DIM / GU_BM, MAX_TILES), 256, 0, stream>>>(
      x_hi, x_lo, w_gate, w_up, topk_w, cursors, tok_list, n_tiles, tile_list, mixed);
  down_mfma<<<dim3(H_DIM / DN_BH, MAX_TILES), 256, 0, stream>>>(
      w_down, mixed, cursors, tok_list, n_tiles, tile_list, out);
}